// Round 1
// baseline (2983.868 us; speedup 1.0000x reference)
//
#include <hip/hip_runtime.h>
#include <hip/hip_bf16.h>

// ---------------- constants (match reference) ----------------
#define DIM_IN 1000
#define HEADS 8
#define HID 8
#define HC1 64          // HEADS*HID
#define DIM_OUT 32
#define HC3 256         // HEADS*DIM_OUT
#define NEG_SLOPE 0.2f

// ---------------- float atomic max via monotone uint flip ----------------
__device__ __forceinline__ unsigned fl_flip(float f) {
    unsigned u = __float_as_uint(f);
    return (u & 0x80000000u) ? ~u : (u | 0x80000000u);
}
__device__ __forceinline__ float fl_unflip(unsigned u) {
    return (u & 0x80000000u) ? __uint_as_float(u ^ 0x80000000u)
                             : __uint_as_float(~u);
}

// ---------------- GEMM1: out[N,128] = x[N,1000] @ [W1 | W2a] ----------------
// cols 0..63 -> hp1, cols 64..127 -> p2
__global__ __launch_bounds__(256) void gemm_x_fused(
    const float* __restrict__ x, const float* __restrict__ W1,
    const float* __restrict__ W2, float* __restrict__ hp1,
    float* __restrict__ p2, int N)
{
    __shared__ float xs[32][32];
    __shared__ __align__(16) float ws[32][128];
    const int tid = threadIdx.x;
    const int rowbase = blockIdx.x * 32;
    const int tr = tid >> 5;   // 0..7  -> rows tr*4..tr*4+3
    const int tc = tid & 31;   // 0..31 -> cols tc*4..tc*4+3
    float4 acc[4] = {};

    for (int k0 = 0; k0 < DIM_IN; k0 += 32) {
        // x tile 32x32 (1024 elems, 4/thread)
#pragma unroll
        for (int i = 0; i < 4; i++) {
            int idx = tid + i * 256;
            int r = idx >> 5, kk = idx & 31;
            int gr = rowbase + r, gk = k0 + kk;
            xs[r][kk] = (gr < N && gk < DIM_IN) ? x[(size_t)gr * DIM_IN + gk] : 0.f;
        }
        // W tile 32x128 (4096 elems, 16/thread)
#pragma unroll
        for (int i = 0; i < 16; i++) {
            int idx = tid + i * 256;
            int kk = idx >> 7, col = idx & 127;
            int gk = k0 + kk;
            float v = 0.f;
            if (gk < DIM_IN)
                v = (col < 64) ? W1[gk * 64 + col] : W2[gk * 64 + (col - 64)];
            ws[kk][col] = v;
        }
        __syncthreads();
#pragma unroll
        for (int kk = 0; kk < 32; kk++) {
            float4 b = ((const float4*)ws[kk])[tc];
            float a0 = xs[tr * 4 + 0][kk];
            float a1 = xs[tr * 4 + 1][kk];
            float a2 = xs[tr * 4 + 2][kk];
            float a3 = xs[tr * 4 + 3][kk];
            acc[0].x += a0 * b.x; acc[0].y += a0 * b.y; acc[0].z += a0 * b.z; acc[0].w += a0 * b.w;
            acc[1].x += a1 * b.x; acc[1].y += a1 * b.y; acc[1].z += a1 * b.z; acc[1].w += a1 * b.w;
            acc[2].x += a2 * b.x; acc[2].y += a2 * b.y; acc[2].z += a2 * b.z; acc[2].w += a2 * b.w;
            acc[3].x += a3 * b.x; acc[3].y += a3 * b.y; acc[3].z += a3 * b.z; acc[3].w += a3 * b.w;
        }
        __syncthreads();
    }
#pragma unroll
    for (int i = 0; i < 4; i++) {
        int gr = rowbase + tr * 4 + i;
        if (gr >= N) continue;
        int col = tc * 4;
        const float v[4] = {acc[i].x, acc[i].y, acc[i].z, acc[i].w};
#pragma unroll
        for (int j = 0; j < 4; j++) {
            int c = col + j;
            if (c < 64) hp1[(size_t)gr * 64 + c] = v[j];
            else        p2 [(size_t)gr * 64 + (c - 64)] = v[j];
        }
    }
}

// ---------------- small GEMM, K=64, NC=64, out += A@W ----------------
__global__ __launch_bounds__(256) void gemm_k64_n64_acc(
    const float* __restrict__ A, const float* __restrict__ W,
    float* __restrict__ out, int N)
{
    __shared__ float as_[16][65];
    const int tid = threadIdx.x;
    const int rb = blockIdx.x * 16;
#pragma unroll
    for (int i = 0; i < 4; i++) {
        int idx = tid + i * 256;
        int r = idx >> 6, c = idx & 63;
        int gr = rb + r;
        as_[r][c] = (gr < N) ? A[(size_t)gr * 64 + c] : 0.f;
    }
    __syncthreads();
    const int row = tid >> 4;
    const int col = (tid & 15) * 4;
    float4 acc = {0, 0, 0, 0};
#pragma unroll 8
    for (int k = 0; k < 64; k++) {
        float a = as_[row][k];
        float4 w = *(const float4*)&W[k * 64 + col];
        acc.x += a * w.x; acc.y += a * w.y; acc.z += a * w.z; acc.w += a * w.w;
    }
    int gr = rb + row;
    if (gr < N) {
        float* o = &out[(size_t)gr * 64 + col];
        o[0] += acc.x; o[1] += acc.y; o[2] += acc.z; o[3] += acc.w;
    }
}

// ---------------- small GEMM, K=64, NC=256, out = A@W ----------------
__global__ __launch_bounds__(256) void gemm_k64_n256(
    const float* __restrict__ A, const float* __restrict__ W,
    float* __restrict__ out, int N)
{
    __shared__ float as_[16][65];
    const int tid = threadIdx.x;
    const int rb = blockIdx.x * 16;
#pragma unroll
    for (int i = 0; i < 4; i++) {
        int idx = tid + i * 256;
        int r = idx >> 6, c = idx & 63;
        int gr = rb + r;
        as_[r][c] = (gr < N) ? A[(size_t)gr * 64 + c] : 0.f;
    }
    __syncthreads();
    const int tr = tid >> 6;          // 0..3 -> rows tr*4..tr*4+3
    const int col = (tid & 63) * 4;   // 0..252
    float4 acc[4] = {};
#pragma unroll 4
    for (int k = 0; k < 64; k++) {
        float4 w = *(const float4*)&W[k * 256 + col];
#pragma unroll
        for (int i = 0; i < 4; i++) {
            float a = as_[tr * 4 + i][k];
            acc[i].x += a * w.x; acc[i].y += a * w.y; acc[i].z += a * w.z; acc[i].w += a * w.w;
        }
    }
#pragma unroll
    for (int i = 0; i < 4; i++) {
        int gr = rb + tr * 4 + i;
        if (gr < N) *(float4*)&out[(size_t)gr * 256 + col] = acc[i];
    }
}

// ---------------- attention dots: als/ald [N,H] ----------------
template <int C>
__global__ __launch_bounds__(256) void attn_dots(
    const float* __restrict__ h, const float* __restrict__ a_s,
    const float* __restrict__ a_d, float* __restrict__ als,
    float* __restrict__ ald, int NH)
{
    int i = blockIdx.x * blockDim.x + threadIdx.x;  // node*8 + head
    if (i >= NH) return;
    int head = i & 7;
    const float* hp = h + (size_t)i * C;
    float s = 0.f, d = 0.f;
#pragma unroll
    for (int c = 0; c < C; c++) {
        float v = hp[c];
        s += v * a_s[head * C + c];
        d += v * a_d[head * C + c];
    }
    als[i] = s; ald[i] = d;
}

// ---------------- edge pass 1: segment max ----------------
__global__ __launch_bounds__(256) void edge_max_k(
    const int* __restrict__ ei, int E, int Etot,
    const float* __restrict__ als, const float* __restrict__ ald,
    unsigned* __restrict__ m)
{
    int e = blockIdx.x * blockDim.x + threadIdx.x;
    if (e >= Etot) return;
    int s, d;
    if (e < E) { s = ei[e]; d = ei[E + e]; } else { s = d = e - E; }
    float4 s0 = *(const float4*)&als[(size_t)s * 8];
    float4 s1 = *(const float4*)&als[(size_t)s * 8 + 4];
    float4 d0 = *(const float4*)&ald[(size_t)d * 8];
    float4 d1 = *(const float4*)&ald[(size_t)d * 8 + 4];
    float ev[8] = {s0.x + d0.x, s0.y + d0.y, s0.z + d0.z, s0.w + d0.w,
                   s1.x + d1.x, s1.y + d1.y, s1.z + d1.z, s1.w + d1.w};
#pragma unroll
    for (int h = 0; h < 8; h++) {
        float v = ev[h];
        v = (v > 0.f) ? v : NEG_SLOPE * v;
        atomicMax(&m[(size_t)d * 8 + h], fl_flip(v));
    }
}

// ---------------- edge pass 2 (HC=64): scatter ee*h and denom ----------------
__global__ __launch_bounds__(256) void edge_scatter64(
    const int* __restrict__ ei, int E, int Etot,
    const float* __restrict__ als, const float* __restrict__ ald,
    const unsigned* __restrict__ m, const float* __restrict__ h,
    float* __restrict__ agg, float* __restrict__ denom)
{
    int eg = blockIdx.x * 4 + (threadIdx.x >> 6);
    if (eg >= Etot) return;
    int lane = threadIdx.x & 63;
    int s, d;
    if (eg < E) { s = ei[eg]; d = ei[E + eg]; } else { s = d = eg - E; }
    int head = lane >> 3;
    float ev = als[(size_t)s * 8 + head] + ald[(size_t)d * 8 + head];
    ev = (ev > 0.f) ? ev : NEG_SLOPE * ev;
    float mv = fl_unflip(m[(size_t)d * 8 + head]);
    float ee = __expf(ev - mv);
    float hv = h[(size_t)s * 64 + lane];
    atomicAdd(&agg[(size_t)d * 64 + lane], ee * hv);
    if ((lane & 7) == 0) atomicAdd(&denom[(size_t)d * 8 + head], ee);
}

// ---------------- edge pass 2 (HC=256): one block per edge ----------------
__global__ __launch_bounds__(256) void edge_scatter256(
    const int* __restrict__ ei, int E, int Etot,
    const float* __restrict__ als, const float* __restrict__ ald,
    const unsigned* __restrict__ m, const float* __restrict__ h,
    float* __restrict__ agg, float* __restrict__ denom)
{
    int eg = blockIdx.x;
    if (eg >= Etot) return;
    int lane = threadIdx.x;           // 0..255
    int s, d;
    if (eg < E) { s = ei[eg]; d = ei[E + eg]; } else { s = d = eg - E; }
    int head = lane >> 5;
    float ev = als[(size_t)s * 8 + head] + ald[(size_t)d * 8 + head];
    ev = (ev > 0.f) ? ev : NEG_SLOPE * ev;
    float mv = fl_unflip(m[(size_t)d * 8 + head]);
    float ee = __expf(ev - mv);
    float hv = h[(size_t)s * 256 + lane];
    atomicAdd(&agg[(size_t)d * 256 + lane], ee * hv);
    if ((lane & 31) == 0) atomicAdd(&denom[(size_t)d * 8 + head], ee);
}

// ---------------- finalize layers 1,2: divide, bias, ELU ----------------
__global__ __launch_bounds__(256) void finalize_elu(
    const float* __restrict__ agg, const float* __restrict__ denom,
    const float* __restrict__ bias, float* __restrict__ hout, int total)
{
    int i = blockIdx.x * blockDim.x + threadIdx.x;
    if (i >= total) return;
    int node = i >> 6, j = i & 63, head = j >> 3;
    float v = agg[i] / (denom[(size_t)node * 8 + head] + 1e-16f) + bias[j];
    hout[i] = (v > 0.f) ? v : (__expf(v) - 1.f);
}

// ---------------- finalize layer 3: mean heads, bias, log_softmax ----------------
__global__ __launch_bounds__(256) void finalize3(
    const float* __restrict__ agg, const float* __restrict__ denom,
    const float* __restrict__ b3, float* __restrict__ out, int N)
{
    int node = blockIdx.x * 8 + (threadIdx.x >> 5);
    int c = threadIdx.x & 31;
    if (node >= N) return;
    float v = 0.f;
#pragma unroll
    for (int h = 0; h < 8; h++)
        v += agg[(size_t)node * 256 + h * 32 + c] /
             (denom[(size_t)node * 8 + h] + 1e-16f);
    v = v * 0.125f + b3[c];
    float mx = v;
#pragma unroll
    for (int o = 16; o; o >>= 1) mx = fmaxf(mx, __shfl_xor(mx, o, 32));
    float ex = __expf(v - mx);
    float sm = ex;
#pragma unroll
    for (int o = 16; o; o >>= 1) sm += __shfl_xor(sm, o, 32);
    out[(size_t)node * 32 + c] = v - mx - __logf(sm);
}

// ---------------- host launch ----------------
extern "C" void kernel_launch(void* const* d_in, const int* in_sizes, int n_in,
                              void* d_out, int out_size, void* d_ws, size_t ws_size,
                              hipStream_t stream)
{
    const float* x   = (const float*)d_in[0];
    const int*   ei  = (const int*)  d_in[1];
    const float* W1  = (const float*)d_in[2];
    const float* as1 = (const float*)d_in[3];
    const float* ad1 = (const float*)d_in[4];
    const float* b1  = (const float*)d_in[5];
    const float* W2  = (const float*)d_in[6];
    const float* as2 = (const float*)d_in[7];
    const float* ad2 = (const float*)d_in[8];
    const float* b2  = (const float*)d_in[9];
    const float* W3  = (const float*)d_in[10];
    const float* as3 = (const float*)d_in[11];
    const float* ad3 = (const float*)d_in[12];
    const float* b3  = (const float*)d_in[13];
    float* out = (float*)d_out;

    const int N = in_sizes[0] / DIM_IN;
    const int E = in_sizes[1] / 2;
    const int Etot = E + N;

    float* ws = (float*)d_ws;
    size_t o = 0;
    float* hp1 = ws + o; o += (size_t)N * 64;    // x@W1
    float* p2  = ws + o; o += (size_t)N * 64;    // x@W2a, then h2pre
    float* h1  = ws + o; o += (size_t)N * 64;
    float* h2  = ws + o; o += (size_t)N * 64;
    float* h3p = ws + o; o += (size_t)N * 256;   // h2@W3
    float* agg = ws + o; o += (size_t)N * 256;   // shared agg buffer
    float* als = ws + o; o += (size_t)N * 8;
    float* ald = ws + o; o += (size_t)N * 8;
    float* den = ws + o; o += (size_t)N * 8;
    unsigned* m = (unsigned*)(ws + o); o += (size_t)N * 8;
    if (o * 4 > ws_size) return;  // workspace too small -> visible failure

    const int TB = 256;
    // fused GEMM over x: hp1 = x@W1, p2 = x@W2[:1000]
    gemm_x_fused<<<(N + 31) / 32, TB, 0, stream>>>(x, W1, W2, hp1, p2, N);

    // ---- layer 1 ----
    attn_dots<8><<<(N * 8 + TB - 1) / TB, TB, 0, stream>>>(hp1, as1, ad1, als, ald, N * 8);
    hipMemsetAsync(m,   0, (size_t)N * 8 * 4, stream);
    hipMemsetAsync(den, 0, (size_t)N * 8 * 4, stream);
    hipMemsetAsync(agg, 0, (size_t)N * 64 * 4, stream);
    edge_max_k<<<(Etot + TB - 1) / TB, TB, 0, stream>>>(ei, E, Etot, als, ald, m);
    edge_scatter64<<<(Etot + 3) / 4, TB, 0, stream>>>(ei, E, Etot, als, ald, m, hp1, agg, den);
    finalize_elu<<<((size_t)N * 64 + TB - 1) / TB, TB, 0, stream>>>(agg, den, b1, h1, N * 64);

    // p2 += h1 @ W2[1000:1064]  -> h2pre
    gemm_k64_n64_acc<<<(N + 15) / 16, TB, 0, stream>>>(h1, W2 + (size_t)DIM_IN * 64, p2, N);

    // ---- layer 2 ----
    attn_dots<8><<<(N * 8 + TB - 1) / TB, TB, 0, stream>>>(p2, as2, ad2, als, ald, N * 8);
    hipMemsetAsync(m,   0, (size_t)N * 8 * 4, stream);
    hipMemsetAsync(den, 0, (size_t)N * 8 * 4, stream);
    hipMemsetAsync(agg, 0, (size_t)N * 64 * 4, stream);
    edge_max_k<<<(Etot + TB - 1) / TB, TB, 0, stream>>>(ei, E, Etot, als, ald, m);
    edge_scatter64<<<(Etot + 3) / 4, TB, 0, stream>>>(ei, E, Etot, als, ald, m, p2, agg, den);
    finalize_elu<<<((size_t)N * 64 + TB - 1) / TB, TB, 0, stream>>>(agg, den, b2, h2, N * 64);

    // h3p = h2 @ W3
    gemm_k64_n256<<<(N + 15) / 16, TB, 0, stream>>>(h2, W3, h3p, N);

    // ---- layer 3 ----
    attn_dots<32><<<(N * 8 + TB - 1) / TB, TB, 0, stream>>>(h3p, as3, ad3, als, ald, N * 8);
    hipMemsetAsync(m,   0, (size_t)N * 8 * 4, stream);
    hipMemsetAsync(den, 0, (size_t)N * 8 * 4, stream);
    hipMemsetAsync(agg, 0, (size_t)N * 256 * 4, stream);
    edge_max_k<<<(Etot + TB - 1) / TB, TB, 0, stream>>>(ei, E, Etot, als, ald, m);
    edge_scatter256<<<Etot, TB, 0, stream>>>(ei, E, Etot, als, ald, m, h3p, agg, den);
    finalize3<<<(N + 7) / 8, TB, 0, stream>>>(agg, den, b3, out, N);
}

// Round 2
// 1317.184 us; speedup vs baseline: 2.2653x; 2.2653x over previous
//
#include <hip/hip_runtime.h>
#include <hip/hip_bf16.h>

// ---------------- constants (match reference) ----------------
#define DIM_IN 1000
#define HEADS 8
#define HID 8
#define DIM_OUT 32
#define NEG_SLOPE 0.2f

// ---------------- GEMM1: out[N,128] = x[N,1000] @ [W1 | W2a] ----------------
// cols 0..63 -> hp1, cols 64..127 -> p2
__global__ __launch_bounds__(256) void gemm_x_fused(
    const float* __restrict__ x, const float* __restrict__ W1,
    const float* __restrict__ W2, float* __restrict__ hp1,
    float* __restrict__ p2, int N)
{
    __shared__ float xs[32][32];
    __shared__ __align__(16) float ws[32][128];
    const int tid = threadIdx.x;
    const int rowbase = blockIdx.x * 32;
    const int tr = tid >> 5;   // 0..7  -> rows tr*4..tr*4+3
    const int tc = tid & 31;   // 0..31 -> cols tc*4..tc*4+3
    float4 acc[4] = {};

    for (int k0 = 0; k0 < DIM_IN; k0 += 32) {
#pragma unroll
        for (int i = 0; i < 4; i++) {
            int idx = tid + i * 256;
            int r = idx >> 5, kk = idx & 31;
            int gr = rowbase + r, gk = k0 + kk;
            xs[r][kk] = (gr < N && gk < DIM_IN) ? x[(size_t)gr * DIM_IN + gk] : 0.f;
        }
#pragma unroll
        for (int i = 0; i < 16; i++) {
            int idx = tid + i * 256;
            int kk = idx >> 7, col = idx & 127;
            int gk = k0 + kk;
            float v = 0.f;
            if (gk < DIM_IN)
                v = (col < 64) ? W1[gk * 64 + col] : W2[gk * 64 + (col - 64)];
            ws[kk][col] = v;
        }
        __syncthreads();
#pragma unroll
        for (int kk = 0; kk < 32; kk++) {
            float4 b = ((const float4*)ws[kk])[tc];
            float a0 = xs[tr * 4 + 0][kk];
            float a1 = xs[tr * 4 + 1][kk];
            float a2 = xs[tr * 4 + 2][kk];
            float a3 = xs[tr * 4 + 3][kk];
            acc[0].x += a0 * b.x; acc[0].y += a0 * b.y; acc[0].z += a0 * b.z; acc[0].w += a0 * b.w;
            acc[1].x += a1 * b.x; acc[1].y += a1 * b.y; acc[1].z += a1 * b.z; acc[1].w += a1 * b.w;
            acc[2].x += a2 * b.x; acc[2].y += a2 * b.y; acc[2].z += a2 * b.z; acc[2].w += a2 * b.w;
            acc[3].x += a3 * b.x; acc[3].y += a3 * b.y; acc[3].z += a3 * b.z; acc[3].w += a3 * b.w;
        }
        __syncthreads();
    }
#pragma unroll
    for (int i = 0; i < 4; i++) {
        int gr = rowbase + tr * 4 + i;
        if (gr >= N) continue;
        int col = tc * 4;
        const float v[4] = {acc[i].x, acc[i].y, acc[i].z, acc[i].w};
#pragma unroll
        for (int j = 0; j < 4; j++) {
            int c = col + j;
            if (c < 64) hp1[(size_t)gr * 64 + c] = v[j];
            else        p2 [(size_t)gr * 64 + (c - 64)] = v[j];
        }
    }
}

// ---------------- small GEMM, K=64, NC=64, out += A@W ----------------
__global__ __launch_bounds__(256) void gemm_k64_n64_acc(
    const float* __restrict__ A, const float* __restrict__ W,
    float* __restrict__ out, int N)
{
    __shared__ float as_[16][65];
    const int tid = threadIdx.x;
    const int rb = blockIdx.x * 16;
#pragma unroll
    for (int i = 0; i < 4; i++) {
        int idx = tid + i * 256;
        int r = idx >> 6, c = idx & 63;
        int gr = rb + r;
        as_[r][c] = (gr < N) ? A[(size_t)gr * 64 + c] : 0.f;
    }
    __syncthreads();
    const int row = tid >> 4;
    const int col = (tid & 15) * 4;
    float4 acc = {0, 0, 0, 0};
#pragma unroll 8
    for (int k = 0; k < 64; k++) {
        float a = as_[row][k];
        float4 w = *(const float4*)&W[k * 64 + col];
        acc.x += a * w.x; acc.y += a * w.y; acc.z += a * w.z; acc.w += a * w.w;
    }
    int gr = rb + row;
    if (gr < N) {
        float* o = &out[(size_t)gr * 64 + col];
        o[0] += acc.x; o[1] += acc.y; o[2] += acc.z; o[3] += acc.w;
    }
}

// ---------------- small GEMM, K=64, NC=256, out = A@W ----------------
__global__ __launch_bounds__(256) void gemm_k64_n256(
    const float* __restrict__ A, const float* __restrict__ W,
    float* __restrict__ out, int N)
{
    __shared__ float as_[16][65];
    const int tid = threadIdx.x;
    const int rb = blockIdx.x * 16;
#pragma unroll
    for (int i = 0; i < 4; i++) {
        int idx = tid + i * 256;
        int r = idx >> 6, c = idx & 63;
        int gr = rb + r;
        as_[r][c] = (gr < N) ? A[(size_t)gr * 64 + c] : 0.f;
    }
    __syncthreads();
    const int tr = tid >> 6;          // 0..3 -> rows tr*4..tr*4+3
    const int col = (tid & 63) * 4;   // 0..252
    float4 acc[4] = {};
#pragma unroll 4
    for (int k = 0; k < 64; k++) {
        float4 w = *(const float4*)&W[k * 256 + col];
#pragma unroll
        for (int i = 0; i < 4; i++) {
            float a = as_[tr * 4 + i][k];
            acc[i].x += a * w.x; acc[i].y += a * w.y; acc[i].z += a * w.z; acc[i].w += a * w.w;
        }
    }
#pragma unroll
    for (int i = 0; i < 4; i++) {
        int gr = rb + tr * 4 + i;
        if (gr < N) *(float4*)&out[(size_t)gr * 256 + col] = acc[i];
    }
}

// ---------------- attention dots: als/ald [N,H] ----------------
template <int C>
__global__ __launch_bounds__(256) void attn_dots(
    const float* __restrict__ h, const float* __restrict__ a_s,
    const float* __restrict__ a_d, float* __restrict__ als,
    float* __restrict__ ald, int NH)
{
    int i = blockIdx.x * blockDim.x + threadIdx.x;  // node*8 + head
    if (i >= NH) return;
    int head = i & 7;
    const float* hp = h + (size_t)i * C;
    float s = 0.f, d = 0.f;
#pragma unroll
    for (int c = 0; c < C; c++) {
        float v = hp[c];
        s += v * a_s[head * C + c];
        d += v * a_d[head * C + c];
    }
    als[i] = s; ald[i] = d;
}

// ---------------- CSR build ----------------
__global__ __launch_bounds__(256) void csr_hist(
    const int* __restrict__ ei, int E, int Etot, int* __restrict__ deg)
{
    int e = blockIdx.x * blockDim.x + threadIdx.x;
    if (e >= Etot) return;
    int d = (e < E) ? ei[E + e] : e - E;
    atomicAdd(&deg[d], 1);
}

__global__ __launch_bounds__(1024) void csr_scan(
    const int* __restrict__ deg, int* __restrict__ rowptr,
    int* __restrict__ cursor, int N)
{
    __shared__ int partial[1024];
    const int t = threadIdx.x;
    const int chunk = (N + 1023) >> 10;
    const int lo = t * chunk;
    const int hi = min(N, lo + chunk);
    int s = 0;
    for (int i = lo; i < hi; i++) s += deg[i];
    partial[t] = s;
    __syncthreads();
    for (int off = 1; off < 1024; off <<= 1) {
        int v = (t >= off) ? partial[t - off] : 0;
        __syncthreads();
        partial[t] += v;
        __syncthreads();
    }
    int run = (t == 0) ? 0 : partial[t - 1];
    for (int i = lo; i < hi; i++) {
        rowptr[i] = run;
        cursor[i] = run;
        run += deg[i];
    }
    if (t == 1023) rowptr[N] = partial[1023];
}

__global__ __launch_bounds__(256) void csr_fill(
    const int* __restrict__ ei, int E, int Etot,
    int* __restrict__ cursor, int* __restrict__ esrc)
{
    int e = blockIdx.x * blockDim.x + threadIdx.x;
    if (e >= Etot) return;
    int s, d;
    if (e < E) { s = ei[e]; d = ei[E + e]; } else { s = d = e - E; }
    int pos = atomicAdd(&cursor[d], 1);
    esrc[pos] = s;
}

// ---------------- fused gather layer (C=64): online softmax + bias + ELU ----------------
__global__ __launch_bounds__(256) void gat_gather64(
    const int* __restrict__ rowptr, const int* __restrict__ esrc,
    const float* __restrict__ als, const float* __restrict__ ald,
    const float* __restrict__ h, const float* __restrict__ bias,
    float* __restrict__ out, int N)
{
    int node = blockIdx.x * 4 + (threadIdx.x >> 6);
    if (node >= N) return;
    int lane = threadIdx.x & 63;
    int head = lane >> 3;
    int start = rowptr[node], end = rowptr[node + 1];
    float aldv = ald[(size_t)node * 8 + head];
    float m = -1e30f, den = 0.f, acc = 0.f;
    for (int i = start; i < end; i++) {
        int s = esrc[i];
        float e = als[(size_t)s * 8 + head] + aldv;
        e = (e > 0.f) ? e : NEG_SLOPE * e;
        float hv = h[(size_t)s * 64 + lane];
        float nm = fmaxf(m, e);
        float sc = __expf(m - nm);
        float ee = __expf(e - nm);
        acc = acc * sc + ee * hv;
        den = den * sc + ee;
        m = nm;
    }
    float v = acc / (den + 1e-16f) + bias[lane];
    out[(size_t)node * 64 + lane] = (v > 0.f) ? v : (__expf(v) - 1.f);
}

// ---------------- fused gather layer 3 (C=256): online softmax + head-mean
// + bias + log_softmax, one wave per node ----------------
__global__ __launch_bounds__(256) void gat_gather256_final(
    const int* __restrict__ rowptr, const int* __restrict__ esrc,
    const float* __restrict__ als, const float* __restrict__ ald,
    const float* __restrict__ h, const float* __restrict__ b3,
    float* __restrict__ out, int N)
{
    int node = blockIdx.x * 4 + (threadIdx.x >> 6);
    if (node >= N) return;
    int lane = threadIdx.x & 63;
    int head = lane >> 3;           // channels lane*4..lane*4+3 all in this head
    int start = rowptr[node], end = rowptr[node + 1];
    float aldv = ald[(size_t)node * 8 + head];
    float m = -1e30f, den = 0.f;
    float4 acc = {0.f, 0.f, 0.f, 0.f};
    for (int i = start; i < end; i++) {
        int s = esrc[i];
        float e = als[(size_t)s * 8 + head] + aldv;
        e = (e > 0.f) ? e : NEG_SLOPE * e;
        float4 hv = *(const float4*)&h[(size_t)s * 256 + lane * 4];
        float nm = fmaxf(m, e);
        float sc = __expf(m - nm);
        float ee = __expf(e - nm);
        acc.x = acc.x * sc + ee * hv.x;
        acc.y = acc.y * sc + ee * hv.y;
        acc.z = acc.z * sc + ee * hv.z;
        acc.w = acc.w * sc + ee * hv.w;
        den = den * sc + ee;
        m = nm;
    }
    float inv = 1.f / (den + 1e-16f);
    float4 v = {acc.x * inv, acc.y * inv, acc.z * inv, acc.w * inv};
    // head-mean: lanes l, l+8, ..., l+56 hold same 4 classes for different heads
#pragma unroll
    for (int o = 8; o < 64; o <<= 1) {
        v.x += __shfl_xor(v.x, o, 64);
        v.y += __shfl_xor(v.y, o, 64);
        v.z += __shfl_xor(v.z, o, 64);
        v.w += __shfl_xor(v.w, o, 64);
    }
    int cq = (lane & 7) * 4;
    v.x = v.x * 0.125f + b3[cq + 0];
    v.y = v.y * 0.125f + b3[cq + 1];
    v.z = v.z * 0.125f + b3[cq + 2];
    v.w = v.w * 0.125f + b3[cq + 3];
    // log-softmax across the 32 classes held by lanes 0..7 (replicated in each 8-group)
    float mx = fmaxf(fmaxf(v.x, v.y), fmaxf(v.z, v.w));
#pragma unroll
    for (int o = 1; o < 8; o <<= 1) mx = fmaxf(mx, __shfl_xor(mx, o, 64));
    float ex = __expf(v.x - mx) + __expf(v.y - mx) + __expf(v.z - mx) + __expf(v.w - mx);
#pragma unroll
    for (int o = 1; o < 8; o <<= 1) ex += __shfl_xor(ex, o, 64);
    float lse = mx + __logf(ex);
    if (lane < 8) {
        float4 o4 = {v.x - lse, v.y - lse, v.z - lse, v.w - lse};
        *(float4*)&out[(size_t)node * 32 + cq] = o4;
    }
}

// ---------------- host launch ----------------
extern "C" void kernel_launch(void* const* d_in, const int* in_sizes, int n_in,
                              void* d_out, int out_size, void* d_ws, size_t ws_size,
                              hipStream_t stream)
{
    const float* x   = (const float*)d_in[0];
    const int*   ei  = (const int*)  d_in[1];
    const float* W1  = (const float*)d_in[2];
    const float* as1 = (const float*)d_in[3];
    const float* ad1 = (const float*)d_in[4];
    const float* b1  = (const float*)d_in[5];
    const float* W2  = (const float*)d_in[6];
    const float* as2 = (const float*)d_in[7];
    const float* ad2 = (const float*)d_in[8];
    const float* b2  = (const float*)d_in[9];
    const float* W3  = (const float*)d_in[10];
    const float* as3 = (const float*)d_in[11];
    const float* ad3 = (const float*)d_in[12];
    const float* b3  = (const float*)d_in[13];
    float* out = (float*)d_out;

    const int N = in_sizes[0] / DIM_IN;
    const int E = in_sizes[1] / 2;
    const int Etot = E + N;

    float* ws = (float*)d_ws;
    size_t o = 0;
    float* hp1 = ws + o; o += (size_t)N * 64;    // x@W1
    float* p2  = ws + o; o += (size_t)N * 64;    // x@W2a, then h2pre
    float* h1  = ws + o; o += (size_t)N * 64;
    float* h2  = ws + o; o += (size_t)N * 64;
    float* h3p = ws + o; o += (size_t)N * 256;   // h2@W3
    float* als = ws + o; o += (size_t)N * 8;
    float* ald = ws + o; o += (size_t)N * 8;
    int* deg    = (int*)(ws + o); o += N;
    int* rowptr = (int*)(ws + o); o += N + 1;
    int* cursor = (int*)(ws + o); o += N;
    int* esrc   = (int*)(ws + o); o += Etot;
    if (o * 4 > ws_size) return;  // workspace too small -> visible failure

    const int TB = 256;

    // fused GEMM over x: hp1 = x@W1, p2 = x@W2[:1000]
    gemm_x_fused<<<(N + 31) / 32, TB, 0, stream>>>(x, W1, W2, hp1, p2, N);

    // CSR build (graph shared by all 3 layers)
    hipMemsetAsync(deg, 0, (size_t)N * 4, stream);
    csr_hist<<<(Etot + TB - 1) / TB, TB, 0, stream>>>(ei, E, Etot, deg);
    csr_scan<<<1, 1024, 0, stream>>>(deg, rowptr, cursor, N);
    csr_fill<<<(Etot + TB - 1) / TB, TB, 0, stream>>>(ei, E, Etot, cursor, esrc);

    // ---- layer 1 ----
    attn_dots<8><<<(N * 8 + TB - 1) / TB, TB, 0, stream>>>(hp1, as1, ad1, als, ald, N * 8);
    gat_gather64<<<(N + 3) / 4, TB, 0, stream>>>(rowptr, esrc, als, ald, hp1, b1, h1, N);

    // p2 += h1 @ W2[1000:1064]  -> h2pre
    gemm_k64_n64_acc<<<(N + 15) / 16, TB, 0, stream>>>(h1, W2 + (size_t)DIM_IN * 64, p2, N);

    // ---- layer 2 ----
    attn_dots<8><<<(N * 8 + TB - 1) / TB, TB, 0, stream>>>(p2, as2, ad2, als, ald, N * 8);
    gat_gather64<<<(N + 3) / 4, TB, 0, stream>>>(rowptr, esrc, als, ald, p2, b2, h2, N);

    // h3p = h2 @ W3
    gemm_k64_n256<<<(N + 15) / 16, TB, 0, stream>>>(h2, W3, h3p, N);

    // ---- layer 3 ----
    attn_dots<32><<<(N * 8 + TB - 1) / TB, TB, 0, stream>>>(h3p, as3, ad3, als, ald, N * 8);
    gat_gather256_final<<<(N + 3) / 4, TB, 0, stream>>>(rowptr, esrc, als, ald, h3p, b3, out, N);
}

// Round 3
// 845.024 us; speedup vs baseline: 3.5311x; 1.5588x over previous
//
#include <hip/hip_runtime.h>
#include <hip/hip_bf16.h>

// ---------------- constants (match reference) ----------------
#define DIM_IN 1000
#define HEADS 8
#define HID 8
#define DIM_OUT 32
#define NEG_SLOPE 0.2f

// ---------------- GEMM1: out[N,128] = x[N,1000] @ [W1 | W2a] ----------------
// 128x128 tile, 8x8 per thread, reg-prefetched global->LDS staging.
// cols 0..63 -> hp1, cols 64..127 -> p2
__global__ __launch_bounds__(256) void gemm_x_fused(
    const float* __restrict__ x, const float* __restrict__ W1,
    const float* __restrict__ W2, float* __restrict__ hp1,
    float* __restrict__ p2, int N)
{
    __shared__ float xs[128][33];                 // [row][k], +1 pad banks
    __shared__ __align__(16) float ws[32][128];   // [k][col]
    const int tid = threadIdx.x;
    const int rowbase = blockIdx.x * 128;

    const int row0 = (tid >> 4) * 8;   // 8 rows per thread
    const int cA = (tid & 15) * 4;     // cols cA..cA+3 (-> hp1)
    // cols 64+cA..64+cA+3 (-> p2)

    float accA[8][4] = {};
    float accB[8][4] = {};
    float4 rx[4], rw[4];

    // ---- load tile t into registers ----
    auto load_tile = [&](int k0) {
#pragma unroll
        for (int i = 0; i < 4; i++) {
            int f4 = tid + i * 256;
            int r = f4 >> 3;             // 0..127
            int kq = (f4 & 7) * 4;       // 0,4,...,28
            int gr = rowbase + r, gk = k0 + kq;
            float4 v = {0.f, 0.f, 0.f, 0.f};
            if (gr < N && gk + 3 < DIM_IN)
                v = *(const float4*)&x[(size_t)gr * DIM_IN + gk];
            rx[i] = v;
        }
#pragma unroll
        for (int i = 0; i < 4; i++) {
            int f4 = tid + i * 256;
            int kk = f4 >> 5;            // 0..31
            int cq = (f4 & 31) * 4;      // 0..124
            int gk = k0 + kk;
            float4 v = {0.f, 0.f, 0.f, 0.f};
            if (gk < DIM_IN)
                v = (cq < 64) ? *(const float4*)&W1[(size_t)gk * 64 + cq]
                              : *(const float4*)&W2[(size_t)gk * 64 + (cq - 64)];
            rw[i] = v;
        }
    };

    auto store_tile = [&]() {
#pragma unroll
        for (int i = 0; i < 4; i++) {
            int f4 = tid + i * 256;
            int r = f4 >> 3, kq = (f4 & 7) * 4;
            xs[r][kq + 0] = rx[i].x;
            xs[r][kq + 1] = rx[i].y;
            xs[r][kq + 2] = rx[i].z;
            xs[r][kq + 3] = rx[i].w;
        }
#pragma unroll
        for (int i = 0; i < 4; i++) {
            int f4 = tid + i * 256;
            int kk = f4 >> 5, cq = (f4 & 31) * 4;
            *(float4*)&ws[kk][cq] = rw[i];
        }
    };

    load_tile(0);
    const int NT = (DIM_IN + 31) / 32;   // 32
    for (int t = 0; t < NT; t++) {
        __syncthreads();                 // prev compute done
        store_tile();
        __syncthreads();
        if (t + 1 < NT) load_tile((t + 1) * 32);   // prefetch (hidden under compute)
#pragma unroll
        for (int kk = 0; kk < 32; kk++) {
            float4 b0 = *(const float4*)&ws[kk][cA];
            float4 b1 = *(const float4*)&ws[kk][64 + cA];
#pragma unroll
            for (int r = 0; r < 8; r++) {
                float a = xs[row0 + r][kk];
                accA[r][0] += a * b0.x; accA[r][1] += a * b0.y;
                accA[r][2] += a * b0.z; accA[r][3] += a * b0.w;
                accB[r][0] += a * b1.x; accB[r][1] += a * b1.y;
                accB[r][2] += a * b1.z; accB[r][3] += a * b1.w;
            }
        }
    }

#pragma unroll
    for (int r = 0; r < 8; r++) {
        int gr = rowbase + row0 + r;
        if (gr >= N) continue;
        *(float4*)&hp1[(size_t)gr * 64 + cA] = *(float4*)accA[r];
        *(float4*)&p2 [(size_t)gr * 64 + cA] = *(float4*)accB[r];
    }
}

// ---------------- small GEMM, K=64, NC=64, out += A@W ----------------
__global__ __launch_bounds__(256) void gemm_k64_n64_acc(
    const float* __restrict__ A, const float* __restrict__ W,
    float* __restrict__ out, int N)
{
    __shared__ float as_[16][65];
    const int tid = threadIdx.x;
    const int rb = blockIdx.x * 16;
#pragma unroll
    for (int i = 0; i < 4; i++) {
        int idx = tid + i * 256;
        int r = idx >> 6, c = idx & 63;
        int gr = rb + r;
        as_[r][c] = (gr < N) ? A[(size_t)gr * 64 + c] : 0.f;
    }
    __syncthreads();
    const int row = tid >> 4;
    const int col = (tid & 15) * 4;
    float4 acc = {0, 0, 0, 0};
#pragma unroll 8
    for (int k = 0; k < 64; k++) {
        float a = as_[row][k];
        float4 w = *(const float4*)&W[k * 64 + col];
        acc.x += a * w.x; acc.y += a * w.y; acc.z += a * w.z; acc.w += a * w.w;
    }
    int gr = rb + row;
    if (gr < N) {
        float* o = &out[(size_t)gr * 64 + col];
        o[0] += acc.x; o[1] += acc.y; o[2] += acc.z; o[3] += acc.w;
    }
}

// ---------------- small GEMM, K=64, NC=256, out = A@W ----------------
__global__ __launch_bounds__(256) void gemm_k64_n256(
    const float* __restrict__ A, const float* __restrict__ W,
    float* __restrict__ out, int N)
{
    __shared__ float as_[16][65];
    const int tid = threadIdx.x;
    const int rb = blockIdx.x * 16;
#pragma unroll
    for (int i = 0; i < 4; i++) {
        int idx = tid + i * 256;
        int r = idx >> 6, c = idx & 63;
        int gr = rb + r;
        as_[r][c] = (gr < N) ? A[(size_t)gr * 64 + c] : 0.f;
    }
    __syncthreads();
    const int tr = tid >> 6;          // 0..3 -> rows tr*4..tr*4+3
    const int col = (tid & 63) * 4;   // 0..252
    float4 acc[4] = {};
#pragma unroll 4
    for (int k = 0; k < 64; k++) {
        float4 w = *(const float4*)&W[k * 256 + col];
#pragma unroll
        for (int i = 0; i < 4; i++) {
            float a = as_[tr * 4 + i][k];
            acc[i].x += a * w.x; acc[i].y += a * w.y; acc[i].z += a * w.z; acc[i].w += a * w.w;
        }
    }
#pragma unroll
    for (int i = 0; i < 4; i++) {
        int gr = rb + tr * 4 + i;
        if (gr < N) *(float4*)&out[(size_t)gr * 256 + col] = acc[i];
    }
}

// ---------------- attention dots: als/ald [N,H] ----------------
template <int C>
__global__ __launch_bounds__(256) void attn_dots(
    const float* __restrict__ h, const float* __restrict__ a_s,
    const float* __restrict__ a_d, float* __restrict__ als,
    float* __restrict__ ald, int NH)
{
    int i = blockIdx.x * blockDim.x + threadIdx.x;  // node*8 + head
    if (i >= NH) return;
    int head = i & 7;
    const float* hp = h + (size_t)i * C;
    float s = 0.f, d = 0.f;
#pragma unroll
    for (int c = 0; c < C; c++) {
        float v = hp[c];
        s += v * a_s[head * C + c];
        d += v * a_d[head * C + c];
    }
    als[i] = s; ald[i] = d;
}

// ---------------- CSR build ----------------
__global__ __launch_bounds__(256) void csr_hist(
    const int* __restrict__ ei, int E, int Etot, int* __restrict__ deg)
{
    int e = blockIdx.x * blockDim.x + threadIdx.x;
    if (e >= Etot) return;
    int d = (e < E) ? ei[E + e] : e - E;
    atomicAdd(&deg[d], 1);
}

__global__ __launch_bounds__(1024) void csr_scan(
    const int* __restrict__ deg, int* __restrict__ rowptr,
    int* __restrict__ cursor, int N)
{
    __shared__ int partial[1024];
    const int t = threadIdx.x;
    const int chunk = (N + 1023) >> 10;
    const int lo = t * chunk;
    const int hi = min(N, lo + chunk);
    int s = 0;
    for (int i = lo; i < hi; i++) s += deg[i];
    partial[t] = s;
    __syncthreads();
    for (int off = 1; off < 1024; off <<= 1) {
        int v = (t >= off) ? partial[t - off] : 0;
        __syncthreads();
        partial[t] += v;
        __syncthreads();
    }
    int run = (t == 0) ? 0 : partial[t - 1];
    for (int i = lo; i < hi; i++) {
        rowptr[i] = run;
        cursor[i] = run;
        run += deg[i];
    }
    if (t == 1023) rowptr[N] = partial[1023];
}

__global__ __launch_bounds__(256) void csr_fill(
    const int* __restrict__ ei, int E, int Etot,
    int* __restrict__ cursor, int* __restrict__ esrc)
{
    int e = blockIdx.x * blockDim.x + threadIdx.x;
    if (e >= Etot) return;
    int s, d;
    if (e < E) { s = ei[e]; d = ei[E + e]; } else { s = d = e - E; }
    int pos = atomicAdd(&cursor[d], 1);
    esrc[pos] = s;
}

// ---------------- fused gather layer (C=64): online softmax + bias + ELU ----------------
__global__ __launch_bounds__(256) void gat_gather64(
    const int* __restrict__ rowptr, const int* __restrict__ esrc,
    const float* __restrict__ als, const float* __restrict__ ald,
    const float* __restrict__ h, const float* __restrict__ bias,
    float* __restrict__ out, int N)
{
    int node = blockIdx.x * 4 + (threadIdx.x >> 6);
    if (node >= N) return;
    int lane = threadIdx.x & 63;
    int head = lane >> 3;
    int start = rowptr[node], end = rowptr[node + 1];
    float aldv = ald[(size_t)node * 8 + head];
    float m = -1e30f, den = 0.f, acc = 0.f;
    for (int i = start; i < end; i++) {
        int s = esrc[i];
        float e = als[(size_t)s * 8 + head] + aldv;
        e = (e > 0.f) ? e : NEG_SLOPE * e;
        float hv = h[(size_t)s * 64 + lane];
        float nm = fmaxf(m, e);
        float sc = __expf(m - nm);
        float ee = __expf(e - nm);
        acc = acc * sc + ee * hv;
        den = den * sc + ee;
        m = nm;
    }
    float v = acc / (den + 1e-16f) + bias[lane];
    out[(size_t)node * 64 + lane] = (v > 0.f) ? v : (__expf(v) - 1.f);
}

// ---------------- fused gather layer 3 (C=256): online softmax + head-mean
// + bias + log_softmax, one wave per node ----------------
__global__ __launch_bounds__(256) void gat_gather256_final(
    const int* __restrict__ rowptr, const int* __restrict__ esrc,
    const float* __restrict__ als, const float* __restrict__ ald,
    const float* __restrict__ h, const float* __restrict__ b3,
    float* __restrict__ out, int N)
{
    int node = blockIdx.x * 4 + (threadIdx.x >> 6);
    if (node >= N) return;
    int lane = threadIdx.x & 63;
    int head = lane >> 3;           // channels lane*4..lane*4+3 all in this head
    int start = rowptr[node], end = rowptr[node + 1];
    float aldv = ald[(size_t)node * 8 + head];
    float m = -1e30f, den = 0.f;
    float4 acc = {0.f, 0.f, 0.f, 0.f};
    for (int i = start; i < end; i++) {
        int s = esrc[i];
        float e = als[(size_t)s * 8 + head] + aldv;
        e = (e > 0.f) ? e : NEG_SLOPE * e;
        float4 hv = *(const float4*)&h[(size_t)s * 256 + lane * 4];
        float nm = fmaxf(m, e);
        float sc = __expf(m - nm);
        float ee = __expf(e - nm);
        acc.x = acc.x * sc + ee * hv.x;
        acc.y = acc.y * sc + ee * hv.y;
        acc.z = acc.z * sc + ee * hv.z;
        acc.w = acc.w * sc + ee * hv.w;
        den = den * sc + ee;
        m = nm;
    }
    float inv = 1.f / (den + 1e-16f);
    float4 v = {acc.x * inv, acc.y * inv, acc.z * inv, acc.w * inv};
    // head-mean: lanes l, l+8, ..., l+56 hold same 4 classes for different heads
#pragma unroll
    for (int o = 8; o < 64; o <<= 1) {
        v.x += __shfl_xor(v.x, o, 64);
        v.y += __shfl_xor(v.y, o, 64);
        v.z += __shfl_xor(v.z, o, 64);
        v.w += __shfl_xor(v.w, o, 64);
    }
    int cq = (lane & 7) * 4;
    v.x = v.x * 0.125f + b3[cq + 0];
    v.y = v.y * 0.125f + b3[cq + 1];
    v.z = v.z * 0.125f + b3[cq + 2];
    v.w = v.w * 0.125f + b3[cq + 3];
    // log-softmax across the 32 classes held by lanes 0..7 (replicated in each 8-group)
    float mx = fmaxf(fmaxf(v.x, v.y), fmaxf(v.z, v.w));
#pragma unroll
    for (int o = 1; o < 8; o <<= 1) mx = fmaxf(mx, __shfl_xor(mx, o, 64));
    float ex = __expf(v.x - mx) + __expf(v.y - mx) + __expf(v.z - mx) + __expf(v.w - mx);
#pragma unroll
    for (int o = 1; o < 8; o <<= 1) ex += __shfl_xor(ex, o, 64);
    float lse = mx + __logf(ex);
    if (lane < 8) {
        float4 o4 = {v.x - lse, v.y - lse, v.z - lse, v.w - lse};
        *(float4*)&out[(size_t)node * 32 + cq] = o4;
    }
}

// ---------------- host launch ----------------
extern "C" void kernel_launch(void* const* d_in, const int* in_sizes, int n_in,
                              void* d_out, int out_size, void* d_ws, size_t ws_size,
                              hipStream_t stream)
{
    const float* x   = (const float*)d_in[0];
    const int*   ei  = (const int*)  d_in[1];
    const float* W1  = (const float*)d_in[2];
    const float* as1 = (const float*)d_in[3];
    const float* ad1 = (const float*)d_in[4];
    const float* b1  = (const float*)d_in[5];
    const float* W2  = (const float*)d_in[6];
    const float* as2 = (const float*)d_in[7];
    const float* ad2 = (const float*)d_in[8];
    const float* b2  = (const float*)d_in[9];
    const float* W3  = (const float*)d_in[10];
    const float* as3 = (const float*)d_in[11];
    const float* ad3 = (const float*)d_in[12];
    const float* b3  = (const float*)d_in[13];
    float* out = (float*)d_out;

    const int N = in_sizes[0] / DIM_IN;
    const int E = in_sizes[1] / 2;
    const int Etot = E + N;

    float* ws = (float*)d_ws;
    size_t o = 0;
    float* hp1 = ws + o; o += (size_t)N * 64;    // x@W1
    float* p2  = ws + o; o += (size_t)N * 64;    // x@W2a, then h2pre
    float* h1  = ws + o; o += (size_t)N * 64;
    float* h2  = ws + o; o += (size_t)N * 64;
    float* h3p = ws + o; o += (size_t)N * 256;   // h2@W3
    float* als = ws + o; o += (size_t)N * 8;
    float* ald = ws + o; o += (size_t)N * 8;
    int* deg    = (int*)(ws + o); o += N;
    int* rowptr = (int*)(ws + o); o += N + 1;
    int* cursor = (int*)(ws + o); o += N;
    int* esrc   = (int*)(ws + o); o += Etot;
    if (o * 4 > ws_size) return;  // workspace too small -> visible failure

    const int TB = 256;

    // fused GEMM over x: hp1 = x@W1, p2 = x@W2[:1000]
    gemm_x_fused<<<(N + 127) / 128, TB, 0, stream>>>(x, W1, W2, hp1, p2, N);

    // CSR build (graph shared by all 3 layers)
    hipMemsetAsync(deg, 0, (size_t)N * 4, stream);
    csr_hist<<<(Etot + TB - 1) / TB, TB, 0, stream>>>(ei, E, Etot, deg);
    csr_scan<<<1, 1024, 0, stream>>>(deg, rowptr, cursor, N);
    csr_fill<<<(Etot + TB - 1) / TB, TB, 0, stream>>>(ei, E, Etot, cursor, esrc);

    // ---- layer 1 ----
    attn_dots<8><<<(N * 8 + TB - 1) / TB, TB, 0, stream>>>(hp1, as1, ad1, als, ald, N * 8);
    gat_gather64<<<(N + 3) / 4, TB, 0, stream>>>(rowptr, esrc, als, ald, hp1, b1, h1, N);

    // p2 += h1 @ W2[1000:1064]  -> h2pre
    gemm_k64_n64_acc<<<(N + 15) / 16, TB, 0, stream>>>(h1, W2 + (size_t)DIM_IN * 64, p2, N);

    // ---- layer 2 ----
    attn_dots<8><<<(N * 8 + TB - 1) / TB, TB, 0, stream>>>(p2, as2, ad2, als, ald, N * 8);
    gat_gather64<<<(N + 3) / 4, TB, 0, stream>>>(rowptr, esrc, als, ald, p2, b2, h2, N);

    // h3p = h2 @ W3
    gemm_k64_n256<<<(N + 15) / 16, TB, 0, stream>>>(h2, W3, h3p, N);

    // ---- layer 3 ----
    attn_dots<32><<<(N * 8 + TB - 1) / TB, TB, 0, stream>>>(h3p, as3, ad3, als, ald, N * 8);
    gat_gather256_final<<<(N + 3) / 4, TB, 0, stream>>>(rowptr, esrc, als, ald, h3p, b3, out, N);
}